// Round 4
// baseline (634.325 us; speedup 1.0000x reference)
//
#include <hip/hip_runtime.h>
#include <math.h>

#define LN2F 0.6931471805599453f
#define AT 8

typedef _Float16 half_t;
typedef _Float16 half4_t __attribute__((ext_vector_type(4)));
typedef float f32x4 __attribute__((ext_vector_type(4)));

__device__ __forceinline__ float sspf(float z) {
    // ssp(z) = max(z,0) + log(1+exp(-|z|)) - ln2   (fast HW intrinsics)
    return fmaxf(z, 0.f) + __logf(1.f + __expf(-fabsf(z))) - LN2F;
}

__device__ __forceinline__ half4_t cvt4(float x, float y, float z, float w) {
    half4_t r; r[0] = (half_t)x; r[1] = (half_t)y; r[2] = (half_t)z; r[3] = (half_t)w;
    return r;
}

// one fused weight-prep launch: dst[n*Kp+k] = (k<K) ? src[k*128+n] : 0  (f32->f16)
__global__ __launch_bounds__(256) void prep_weights(
    const float* __restrict__ W_in2f, const float* __restrict__ W_f1,
    const float* __restrict__ W_f2, const float* __restrict__ W_o1,
    const float* __restrict__ W_o2,
    half_t* __restrict__ Wt_in2f, half_t* __restrict__ Wt_f1,
    half_t* __restrict__ Wt_f2, half_t* __restrict__ Wt_o1,
    half_t* __restrict__ Wt_o2)
{
    int b = blockIdx.x;
    const float* src; half_t* dst; int K, Kp;
    if (b < 64)       { src = W_in2f; dst = Wt_in2f; K = 128; Kp = 128; }
    else if (b < 80)  { src = W_f1;   dst = Wt_f1;   K = 20;  Kp = 32;  b -= 64; }
    else if (b < 144) { src = W_f2;   dst = Wt_f2;   K = 128; Kp = 128; b -= 80; }
    else if (b < 208) { src = W_o1;   dst = Wt_o1;   K = 128; Kp = 128; b -= 144; }
    else              { src = W_o2;   dst = Wt_o2;   K = 128; Kp = 128; b -= 208; }
    int i = b * 256 + threadIdx.x;
    if (i >= 128 * Kp) return;
    int n = i / Kp, k = i % Kp;
    dst[i] = (k < K) ? (half_t)src[k * 128 + n] : (half_t)0.f;
}

// atom_start[a] = first edge index with idx_i >= a; atom_start[N] = E
__global__ __launch_bounds__(256) void seg_starts(
    const int* __restrict__ idx_i, int* __restrict__ atom_start, int E, int N)
{
    int e = blockIdx.x * 256 + threadIdx.x;
    if (e >= E) return;
    int a = idx_i[e];
    int prev = (e == 0) ? -1 : idx_i[e - 1];
    for (int k = prev + 1; k <= a; ++k) atom_start[k] = e;
    if (e == E - 1)
        for (int k = a + 1; k <= N; ++k) atom_start[k] = E;
}

// C = act(A @ B + bias); A:[nrows,128] f32, Bt f16 (Bt[n][k]=B[k][n])
// mode: 0 = f32 out, 1 = f32 out + ssp, 2 = f16 out (Ch)
__global__ __launch_bounds__(256) void mfma_gemm(
    const float* __restrict__ A, const half_t* __restrict__ Bt,
    const float* __restrict__ bias, float* __restrict__ C,
    half_t* __restrict__ Ch, int nrows, int mode)
{
    const int tid = threadIdx.x;
    const int w = tid >> 6, l = tid & 63, g = l >> 4, ln = l & 15;
    const int r0 = blockIdx.x * 64;

    f32x4 acc[4][2];
    #pragma unroll
    for (int rf = 0; rf < 4; ++rf)
        #pragma unroll
        for (int cf = 0; cf < 2; ++cf) acc[rf][cf] = (f32x4)0.f;

    #pragma unroll
    for (int kk = 0; kk < 8; ++kk) {
        const int kb = kk * 16 + g * 4;
        half4_t a[4];
        #pragma unroll
        for (int rf = 0; rf < 4; ++rf) {
            int r = r0 + rf * 16 + ln;
            int rr = r < nrows ? r : nrows - 1;
            float4 av = *(const float4*)(A + (size_t)rr * 128 + kb);
            a[rf] = cvt4(av.x, av.y, av.z, av.w);
        }
        #pragma unroll
        for (int cf = 0; cf < 2; ++cf) {
            int n = w * 32 + cf * 16 + ln;
            half4_t b = *(const half4_t*)(Bt + (size_t)n * 128 + kb);
            #pragma unroll
            for (int rf = 0; rf < 4; ++rf)
                acc[rf][cf] = __builtin_amdgcn_mfma_f32_16x16x16f16(a[rf], b, acc[rf][cf], 0, 0, 0);
        }
    }

    #pragma unroll
    for (int cf = 0; cf < 2; ++cf) {
        int n = w * 32 + cf * 16 + ln;
        float bv = bias ? bias[n] : 0.f;
        #pragma unroll
        for (int rf = 0; rf < 4; ++rf) {
            #pragma unroll
            for (int reg = 0; reg < 4; ++reg) {
                int r = r0 + rf * 16 + g * 4 + reg;
                if (r < nrows) {
                    float v = acc[rf][cf][reg] + bv;
                    if (mode == 2)      Ch[(size_t)r * 128 + n] = (half_t)v;
                    else if (mode == 1) C[(size_t)r * 128 + n] = sspf(v);
                    else                C[(size_t)r * 128 + n] = v;
                }
            }
        }
    }
}

// Fused edge pipeline: block = 8 atoms, 512 threads (8 waves, wave owns 16 cols).
// All global loads issued at chunk top; LDS writes deferred past the MFMA
// phases (T14); h rows staged coalesced into LDS as f16.
__global__ __launch_bounds__(512, 5) void edge_kernel(
    const float* __restrict__ f_ij, const float* __restrict__ rcut,
    const int* __restrict__ idx_i, const int* __restrict__ idx_j,
    const half_t* __restrict__ Wt_f1, const float* __restrict__ b_f1,
    const half_t* __restrict__ Wt_f2, const float* __restrict__ b_f2,
    const half_t* __restrict__ hh, float* __restrict__ agg,
    const int* __restrict__ atom_start, int E, int N)
{
    __shared__ __align__(16) half_t fsh[2][64][24];   //  6144 B
    __shared__ __align__(16) half_t w1s[64][136];     // 17408 B
    __shared__ __align__(16) half_t hsh[64][136];     // 17408 B
    __shared__ float bins[AT][128];                   //  4096 B
    __shared__ int   jis[2][64];
    __shared__ int   ais[2][64];
    __shared__ float rcs[2][64];

    const int tid = threadIdx.x;
    const int w = tid >> 6, l = tid & 63, g = l >> 4, ln = l & 15;
    const int n = w * 16 + ln;            // this thread's output column
    const int a0 = blockIdx.x * AT;

    for (int i = tid; i < AT * 128; i += 512) ((float*)bins)[i] = 0.f;

    const int lo = atom_start[a0];
    const int hi = atom_start[min(a0 + AT, N)];

    // persistent B fragments (filter weights) in registers
    half4_t b1f[2], b2f[8];
    #pragma unroll
    for (int kk = 0; kk < 2; ++kk)
        b1f[kk] = *(const half4_t*)(Wt_f1 + (size_t)n * 32 + kk * 16 + g * 4);
    #pragma unroll
    for (int kk = 0; kk < 8; ++kk)
        b2f[kk] = *(const half4_t*)(Wt_f2 + (size_t)n * 128 + kk * 16 + g * 4);
    const float bf1v = b_f1[n];
    const float bf2v = b_f2[n];

    // prologue: stage chunk 0 (direct load->write; before first barrier)
    if (lo < hi) {
        if (tid < 320) {
            int e = lo + tid / 5;
            float4 v = (e < E) ? ((const float4*)f_ij)[(size_t)lo * 5 + tid]
                               : make_float4(0.f, 0.f, 0.f, 0.f);
            *(half4_t*)&fsh[0][tid / 5][(tid % 5) * 4] = cvt4(v.x, v.y, v.z, v.w);
        } else if (tid < 384) { int k = tid - 320, e = lo + k; jis[0][k] = (e < E) ? idx_j[e] : 0; }
        else if (tid < 448)   { int k = tid - 384, e = lo + k; ais[0][k] = (e < E) ? idx_i[e] : a0; }
        else                  { int k = tid - 448, e = lo + k; rcs[0][k] = (e < E) ? rcut[e] : 0.f; }
    }

    float run = 0.f; int cur = -1;
    int p = 0;
    for (int c0 = lo; c0 < hi; c0 += 64, p ^= 1) {
        __syncthreads();   // B1: fsh/meta[p] ready; prev epilogue done (hsh, w1s free)

        // ---- issue next-chunk staging loads (writes deferred past phase 2) ----
        const int c1 = c0 + 64;
        float4 fv; int mj = 0, ma = a0; float mr = 0.f;
        const bool nx = (c1 < hi);
        if (nx) {
            if (tid < 320) {
                int e = c1 + tid / 5;
                fv = (e < E) ? ((const float4*)f_ij)[(size_t)c1 * 5 + tid]
                             : make_float4(0.f, 0.f, 0.f, 0.f);
            } else if (tid < 384) { int e = c1 + (tid - 320); mj = (e < E) ? idx_j[e] : 0; }
            else if (tid < 448)   { int e = c1 + (tid - 384); ma = (e < E) ? idx_i[e] : a0; }
            else                  { int e = c1 + (tid - 448); mr = (e < E) ? rcut[e] : 0.f; }
        }

        // ---- issue current-chunk h-row loads (coalesced, f16) ----
        float4 hreg[2];
        #pragma unroll
        for (int it = 0; it < 2; ++it) {
            int item = tid + it * 512;          // 0..1023
            int row = item >> 4, seg = item & 15;
            int ji = jis[p][row];
            hreg[it] = *(const float4*)(hh + (size_t)ji * 128 + seg * 8);
        }

        // ---- phase 1: z = f_ij @ W1 (K=20 padded to 32) ----
        f32x4 z[4];
        #pragma unroll
        for (int rf = 0; rf < 4; ++rf) z[rf] = (f32x4)0.f;
        #pragma unroll
        for (int kk = 0; kk < 2; ++kk) {
            const int kb = kk * 16 + g * 4;
            #pragma unroll
            for (int rf = 0; rf < 4; ++rf) {
                half4_t a = (half4_t)(half_t)0.f;
                if (kb < 20) a = *(const half4_t*)&fsh[p][rf * 16 + ln][kb];
                z[rf] = __builtin_amdgcn_mfma_f32_16x16x16f16(a, b1f[kk], z[rf], 0, 0, 0);
            }
        }
        // w1 = ssp(z + b1) -> LDS
        #pragma unroll
        for (int rf = 0; rf < 4; ++rf)
            #pragma unroll
            for (int reg = 0; reg < 4; ++reg)
                w1s[rf * 16 + g * 4 + reg][n] = (half_t)sspf(z[rf][reg] + bf1v);
        __syncthreads();   // B2: w1s ready

        // ---- phase 2: acc = w1 @ W2 (K=128) ----
        f32x4 acc[4];
        #pragma unroll
        for (int rf = 0; rf < 4; ++rf) acc[rf] = (f32x4)0.f;
        #pragma unroll
        for (int kk = 0; kk < 8; ++kk) {
            const int kb = kk * 16 + g * 4;
            #pragma unroll
            for (int rf = 0; rf < 4; ++rf) {
                half4_t a = *(const half4_t*)&w1s[rf * 16 + ln][kb];
                acc[rf] = __builtin_amdgcn_mfma_f32_16x16x16f16(a, b2f[kk], acc[rf], 0, 0, 0);
            }
        }

        // ---- deferred LDS writes (global-load latency now covered) ----
        #pragma unroll
        for (int it = 0; it < 2; ++it) {
            int item = tid + it * 512;
            int row = item >> 4, seg = item & 15;
            *(float4*)&hsh[row][seg * 8] = hreg[it];
        }
        if (nx) {
            if (tid < 320)
                *(half4_t*)&fsh[p ^ 1][tid / 5][(tid % 5) * 4] = cvt4(fv.x, fv.y, fv.z, fv.w);
            else if (tid < 384) jis[p ^ 1][tid - 320] = mj;
            else if (tid < 448) ais[p ^ 1][tid - 384] = ma;
            else                rcs[p ^ 1][tid - 448] = mr;
        }
        __syncthreads();   // B3: hsh ready

        // ---- epilogue: (+b2)*rcut*h, run-merged LDS binning ----
        #pragma unroll
        for (int rf = 0; rf < 4; ++rf)
            #pragma unroll
            for (int reg = 0; reg < 4; ++reg) {
                int k = rf * 16 + g * 4 + reg;
                bool val = (c0 + k) < hi;
                float rc = val ? rcs[p][k] : 0.f;
                int   ai = val ? ais[p][k] : a0;
                float hv = (float)hsh[k][n];
                float v = (acc[rf][reg] + bf2v) * rc * hv;
                if (ai != cur) {
                    if (cur >= 0) atomicAdd(&bins[cur - a0][n], run);
                    cur = ai; run = v;
                } else run += v;
            }
    }
    if (cur >= 0) atomicAdd(&bins[cur - a0][n], run);
    __syncthreads();

    for (int i = tid; i < AT * 128; i += 512) {
        int at = i >> 7, c = i & 127;
        int arow = a0 + at;
        if (arow < N) agg[(size_t)arow * 128 + c] = bins[at][c];
    }
}

extern "C" void kernel_launch(void* const* d_in, const int* in_sizes, int n_in,
                              void* d_out, int out_size, void* d_ws, size_t ws_size,
                              hipStream_t stream)
{
    const float* x      = (const float*)d_in[0];
    const float* f_ij   = (const float*)d_in[1];
    const float* rcut   = (const float*)d_in[2];
    const int*   idx_i  = (const int*)d_in[3];
    const int*   idx_j  = (const int*)d_in[4];
    const float* W_in2f = (const float*)d_in[5];
    const float* W_f1   = (const float*)d_in[6];
    const float* b_f1   = (const float*)d_in[7];
    const float* W_f2   = (const float*)d_in[8];
    const float* b_f2   = (const float*)d_in[9];
    const float* W_o1   = (const float*)d_in[10];
    const float* b_o1   = (const float*)d_in[11];
    const float* W_o2   = (const float*)d_in[12];
    const float* b_o2   = (const float*)d_in[13];

    const int N = in_sizes[0] / 128;
    const int E = in_sizes[2];

    // ws layout: [0, N*128*4): h as f16 (first half), later t as f32 (full span)
    half_t* h16  = (half_t*)d_ws;                       // [N,128] f16 (aliases t)
    float*  tbuf = (float*)d_ws;                        // [N,128] f32 (after edge)
    half_t* wt   = (half_t*)((char*)d_ws + (size_t)N * 128 * 4);
    half_t* Wt_in2f = wt;                 // 128*128
    half_t* Wt_f1   = wt + 16384;         // 128*32 (K padded 20->32)
    half_t* Wt_f2   = wt + 16384 + 4096;  // 128*128
    half_t* Wt_o1   = Wt_f2 + 16384;      // 128*128
    half_t* Wt_o2   = Wt_o1 + 16384;      // 128*128
    int* atom_start = (int*)(Wt_o2 + 16384);            // N+1 ints

    prep_weights<<<272, 256, 0, stream>>>(W_in2f, W_f1, W_f2, W_o1, W_o2,
                                          Wt_in2f, Wt_f1, Wt_f2, Wt_o1, Wt_o2);
    seg_starts<<<(E + 255) / 256, 256, 0, stream>>>(idx_i, atom_start, E, N);

    const int gn = (N + 63) / 64;
    const int ga = (N + AT - 1) / AT;

    // h = x @ W_in2f  -> f16
    mfma_gemm<<<gn, 256, 0, stream>>>(x, Wt_in2f, nullptr, nullptr, h16, N, 2);

    // fused edge pipeline -> agg (full overwrite of d_out rows)
    edge_kernel<<<ga, 512, 0, stream>>>(f_ij, rcut, idx_i, idx_j,
                                        Wt_f1, b_f1, Wt_f2, b_f2,
                                        h16, (float*)d_out, atom_start, E, N);

    // t = ssp(agg @ W_o1 + b_o1)   (t overwrites h16; h dead)
    mfma_gemm<<<gn, 256, 0, stream>>>((const float*)d_out, Wt_o1, b_o1, tbuf, nullptr, N, 1);

    // out = t @ W_o2 + b_o2
    mfma_gemm<<<gn, 256, 0, stream>>>(tbuf, Wt_o2, b_o2, (float*)d_out, nullptr, N, 0);
}